// Round 15
// baseline (161.906 us; speedup 1.0000x reference)
//
#include <hip/hip_runtime.h>
#include <math.h>

#define Bn 4
#define Cn 256
#define CIn 128
#define Hn 64
#define Wn 64
#define Nn 4096
#define Gn 8
#define CPGn 32
#define EPSc 1e-5f

typedef unsigned short ushort_t;
typedef short bfrag __attribute__((ext_vector_type(8)));       // 8 bf16 (4 VGPRs)
typedef float f32x4 __attribute__((ext_vector_type(4)));
typedef ushort_t u16x8 __attribute__((ext_vector_type(8)));

static __device__ __forceinline__ ushort_t f2bf(float f) {
  unsigned u = __float_as_uint(f);
  return (ushort_t)((u + 0x7FFFu + ((u >> 16) & 1u)) >> 16);   // RNE
}

static __device__ __forceinline__ unsigned cvt_pk_bf16(float lo, float hi) {
  unsigned r;
  asm("v_cvt_pk_bf16_f32 %0, %1, %2" : "=v"(r) : "v"(lo), "v"(hi));
  return r;
}

static __device__ __forceinline__ float bf2f(ushort_t u) {
  return __uint_as_float((unsigned)u << 16);
}

// async global->LDS, 16B per lane; dest = uniform base + lane*16 (HW rule)
static __device__ __forceinline__ void gl_lds16(const ushort_t* g, ushort_t* l) {
  __builtin_amdgcn_global_load_lds(
      (__attribute__((address_space(1))) void*)g,
      (__attribute__((address_space(3))) void*)l, 16, 0, 0);
}

// ---------------- weight prepack (fp32 -> bf16, rearranged) ----------------
__global__ __launch_bounds__(256) void k_prepack(
    const float* __restrict__ w3, const float* __restrict__ thw,
    const float* __restrict__ phw, const float* __restrict__ gww,
    const float* __restrict__ ww,
    ushort_t* __restrict__ w9, ushort_t* __restrict__ wp9,
    ushort_t* __restrict__ wwb) {
  int i = blockIdx.x * 256 + threadIdx.x;
  if (i < 589824) {
    float v = w3[i];
    int co = i / 2304, r = i % 2304, ci = r / 9, tap = r % 9;
    w9[tap * 65536 + co * 256 + ci] = f2bf(v);
  } else if (i < 688128) {
    int j = i - 589824;
    int which = j >> 15, r = j & 32767;
    const float* src = (which == 0) ? thw : (which == 1) ? phw : gww;
    wp9[j] = f2bf(src[r]);
  } else if (i < 720896) {
    int j = i - 688128;
    wwb[j] = f2bf(ww[j]);
  }
}

// ---------------- x transpose: x[b][c][h][w] fp32 -> xbT[b][hw][c] bf16 ----------------
__global__ __launch_bounds__(256) void k_xT(
    const float* __restrict__ x, ushort_t* __restrict__ xbT) {
  __shared__ ushort_t lt[32 * 64];
  const int t = threadIdx.x;
  const int n0 = blockIdx.x * 64, c0 = blockIdx.y * 32, b = blockIdx.z;
#pragma unroll
  for (int p = 0; p < 8; ++p) {
    int c = c0 + p * 4 + (t >> 6);
    int n = n0 + (t & 63);
    lt[(c - c0) * 64 + (t & 63)] = f2bf(x[((size_t)(b * Cn + c)) * Nn + n]);
  }
  __syncthreads();
  {
    int n = t >> 2, cg = t & 3;
    u16x8 pk;
#pragma unroll
    for (int j = 0; j < 8; ++j) pk[j] = lt[(cg * 8 + j) * 64 + n];
    *(u16x8*)(xbT + ((size_t)(b * Nn + n0 + n)) * Cn + c0 + cg * 8) = pk;
  }
}

// ---------------- conv3x3 via implicit-GEMM MFMA (+ fused GN1 partials) ----------------
// staging via gl_lds from xbT (pre-swizzled source), out = bf16 xr_b
__global__ __launch_bounds__(512) void k_conv_mfma(
    const ushort_t* __restrict__ xbT, const ushort_t* __restrict__ w9,
    const float* __restrict__ b3, ushort_t* __restrict__ xr_b,
    float* __restrict__ part) {
  __shared__ __align__(16) ushort_t lx[3 * 66 * 128];   // [dh][wp][ci], byte swz ^((wp&7)<<4)
  const int tid = threadIdx.x;
  const int lane = tid & 63, w = tid >> 6;
  const int ln = lane & 15, lhi = lane >> 4;
  const int h = blockIdx.x, b = blockIdx.y;
  const int wco = w * 32;

  // zero pad columns (wp = 0, 65) once
  for (int i = tid; i < 768; i += 512) {
    int dh = i / 256, r = i % 256, wpz = (r >> 7) ? 65 : 0, ci = r & 127;
    int off = (((dh * 66 + wpz) * 128 + ci) * 2) ^ ((wpz & 7) << 4);
    *(ushort_t*)((char*)lx + off) = 0;
  }

  f32x4 acc[2][4];
#pragma unroll
  for (int mf = 0; mf < 2; ++mf)
#pragma unroll
    for (int nf = 0; nf < 4; ++nf) acc[mf][nf] = (f32x4){0.f, 0.f, 0.f, 0.f};

  for (int cc = 0; cc < 2; ++cc) {
    __syncthreads();                     // prior reads (and pad writes) done
    // stage 3 rows x 64 wp x 128 ci via gl_lds; linear dest, pre-swizzled src
#pragma unroll
    for (int k = 0; k < 6; ++k) {
      int ch = w * 6 + k;                // 0..47 = 3 dh x 16
      int dh = ch >> 4, wq = (ch & 15) * 4;
      int rowl = wq + (lane >> 4);       // (wp-1) in 0..63
      int wp = rowl + 1;
      int hh = h + dh - 1;
      ushort_t* dst = lx + (dh * 66 + wq + 1) * 128;
      if (hh >= 0 && hh < Hn) {
        int srcC = (((lane & 15) ^ (wp & 7)) * 8) + cc * 128;
        gl_lds16(xbT + ((size_t)(b * Nn + hh * Wn + rowl)) * Cn + srcC, dst);
      } else {
        *(uint4*)((char*)lx + (((dh * 66 + wq + 1) * 128 + lane * 8) * 2)) =
            (uint4){0u, 0u, 0u, 0u};
      }
    }
    __syncthreads();                     // drains vmcnt -> tile ready

#pragma unroll
    for (int tap = 0; tap < 9; ++tap) {
      const int dh = tap / 3, dw = tap % 3;
#pragma unroll
      for (int kb = 0; kb < 4; ++kb) {
        const ushort_t* ap = w9 + tap * 65536 + (size_t)(wco + ln) * 256 +
                             cc * 128 + kb * 32 + lhi * 8;
        bfrag af0 = *(const bfrag*)ap;
        bfrag af1 = *(const bfrag*)(ap + 16 * 256);
        __builtin_amdgcn_s_setprio(1);
#pragma unroll
        for (int nf = 0; nf < 4; ++nf) {
          int wp = nf * 16 + ln + dw;
          int off = (((dh * 66 + wp) * 128 + kb * 32 + lhi * 8) * 2) ^ ((wp & 7) << 4);
          bfrag bf = *(const bfrag*)((const char*)lx + off);
          acc[0][nf] = __builtin_amdgcn_mfma_f32_16x16x32_bf16(af0, bf, acc[0][nf], 0, 0, 0);
          acc[1][nf] = __builtin_amdgcn_mfma_f32_16x16x32_bf16(af1, bf, acc[1][nf], 0, 0, 0);
        }
        __builtin_amdgcn_s_setprio(0);
      }
    }
  }

  // epilogue + fused GN1 partials (wave w == channel group w); bf16 out
  float s_ = 0.f, q_ = 0.f;
#pragma unroll
  for (int mf = 0; mf < 2; ++mf) {
    float4 bv = *(const float4*)(b3 + wco + mf * 16 + lhi * 4);
    float bb[4] = {bv.x, bv.y, bv.z, bv.w};
#pragma unroll
    for (int nf = 0; nf < 4; ++nf) {
#pragma unroll
      for (int r = 0; r < 4; ++r) {
        int co = wco + mf * 16 + lhi * 4 + r;
        float v = acc[mf][nf][r] + bb[r];
        xr_b[((size_t)(b * Cn + co)) * Nn + h * Wn + nf * 16 + ln] = f2bf(v);
        s_ += v;
        q_ += v * v;
      }
    }
  }
#pragma unroll
  for (int off = 32; off; off >>= 1) {
    s_ += __shfl_xor(s_, off);
    q_ += __shfl_xor(q_, off);
  }
  if (lane == 0) {
    size_t pi = ((size_t)(b * Gn + w) * 64 + h) * 2;
    part[pi] = s_;
    part[pi + 1] = q_;
  }
}

// ---------------- GN stats final: 64 partials per (b,g) ----------------
__global__ void k_gn_final(const float* __restrict__ part, float* __restrict__ stats) {
  const int t = threadIdx.x;
  if (t < Bn * Gn) {
    float s = 0.f, ss = 0.f;
    for (int j = 0; j < 64; ++j) {
      s += part[(t * 64 + j) * 2];
      ss += part[(t * 64 + j) * 2 + 1];
    }
    const float inv = 1.f / (float)(CPGn * Nn);
    float mean = s * inv;
    float var = ss * inv - mean * mean;
    stats[t * 2] = mean;
    stats[t * 2 + 1] = rsqrtf(var + EPSc);
  }
}

// ---------------- GN1 apply + ReLU -> xs_b (bf16 [C][N]) and xsT (bf16 [N][C]) ----------------
__global__ __launch_bounds__(256) void k_gn1_apply_t(
    const ushort_t* __restrict__ xr_b, const float* __restrict__ stats,
    const float* __restrict__ gw, const float* __restrict__ gb,
    ushort_t* __restrict__ xs_b, ushort_t* __restrict__ xsT) {
  __shared__ ushort_t lt[32 * 64];
  const int t = threadIdx.x;
  const int n0 = blockIdx.x * 64, c0 = blockIdx.y * 32, b = blockIdx.z;
  {
    int c = c0 + (t >> 3);
    int nc = (t & 7) * 8;
    int bg = b * Gn + (c >> 5);
    float mean = stats[bg * 2], rstd = stats[bg * 2 + 1];
    float sc = gw[c] * rstd;
    float sb = gb[c] - mean * sc;
    size_t idx = ((size_t)(b * Cn + c)) * Nn + n0 + nc;
    u16x8 v = *(const u16x8*)(xr_b + idx);
    u16x8 o;
#pragma unroll
    for (int j = 0; j < 8; ++j)
      o[j] = f2bf(fmaxf(bf2f(v[j]) * sc + sb, 0.f));
    *(u16x8*)(xs_b + idx) = o;
#pragma unroll
    for (int j = 0; j < 8; ++j) lt[(c - c0) * 64 + nc + j] = o[j];
  }
  __syncthreads();
  {
    int n = t >> 2, cg = t & 3;
    u16x8 pk;
#pragma unroll
    for (int j = 0; j < 8; ++j) pk[j] = lt[(cg * 8 + j) * 64 + n];
    *(u16x8*)(xsT + ((size_t)(b * Nn + n0 + n)) * Cn + c0 + cg * 8) = pk;
  }
}

// ---------------- projections via MFMA ----------------
__global__ __launch_bounds__(256) void k_proj_mfma(
    const ushort_t* __restrict__ xsT, const ushort_t* __restrict__ wp9,
    const float* __restrict__ thb, const float* __restrict__ phb,
    const float* __restrict__ gbb,
    ushort_t* __restrict__ theta_b, ushort_t* __restrict__ phi_b,
    ushort_t* __restrict__ g_b) {
  __shared__ __align__(16) ushort_t lxs[64 * 256];   // [n][c], swz ^((n&7)<<4)
  const int tid = threadIdx.x;
  const int lane = tid & 63, w = tid >> 6;
  const int ln = lane & 15, lhi = lane >> 4;
  const int n0 = blockIdx.x * 64, which = blockIdx.y, b = blockIdx.z;
  const int wci = w * 32;

  for (int i = tid; i < 2048; i += 256) {
    int n = i >> 5, cchunk = (i & 31) * 8;
    uint4 v = *(const uint4*)(xsT + ((size_t)(b * Nn + n0 + n)) * Cn + cchunk);
    int off = ((n * 256 + cchunk) * 2) ^ ((n & 7) << 4);
    *(uint4*)((char*)lxs + off) = v;
  }
  __syncthreads();

  f32x4 acc[2][4];
#pragma unroll
  for (int mf = 0; mf < 2; ++mf)
#pragma unroll
    for (int nf = 0; nf < 4; ++nf) acc[mf][nf] = (f32x4){0.f, 0.f, 0.f, 0.f};

#pragma unroll
  for (int kb = 0; kb < 8; ++kb) {
    const ushort_t* ap = wp9 + which * 32768 + (size_t)(wci + ln) * 256 + kb * 32 + lhi * 8;
    bfrag af0 = *(const bfrag*)ap;
    bfrag af1 = *(const bfrag*)(ap + 16 * 256);
    __builtin_amdgcn_s_setprio(1);
#pragma unroll
    for (int nf = 0; nf < 4; ++nf) {
      int n = nf * 16 + ln;
      int off = ((n * 256 + kb * 32 + lhi * 8) * 2) ^ ((n & 7) << 4);
      bfrag bf = *(const bfrag*)((const char*)lxs + off);
      acc[0][nf] = __builtin_amdgcn_mfma_f32_16x16x32_bf16(af0, bf, acc[0][nf], 0, 0, 0);
      acc[1][nf] = __builtin_amdgcn_mfma_f32_16x16x32_bf16(af1, bf, acc[1][nf], 0, 0, 0);
    }
    __builtin_amdgcn_s_setprio(0);
  }

  const float* bs = (which == 0) ? thb : (which == 1) ? phb : gbb;
#pragma unroll
  for (int mf = 0; mf < 2; ++mf) {
    float4 bv = *(const float4*)(bs + wci + mf * 16 + lhi * 4);
    float bb[4] = {bv.x, bv.y, bv.z, bv.w};
    if (which < 2) {
      ushort_t* ob = ((which == 0) ? theta_b : phi_b) + (size_t)b * Nn * CIn;
#pragma unroll
      for (int nf = 0; nf < 4; ++nf) {
        int n = n0 + nf * 16 + ln;
        unsigned lo = (unsigned)f2bf(acc[mf][nf][0] + bb[0]) |
                      ((unsigned)f2bf(acc[mf][nf][1] + bb[1]) << 16);
        unsigned hi = (unsigned)f2bf(acc[mf][nf][2] + bb[2]) |
                      ((unsigned)f2bf(acc[mf][nf][3] + bb[3]) << 16);
        ushort_t* base = ob + (size_t)n * CIn + wci + mf * 16 + lhi * 4;
        *(unsigned*)base = lo;
        *(unsigned*)(base + 2) = hi;
      }
    } else {
      ushort_t* ob = g_b + (size_t)b * CIn * Nn;
#pragma unroll
      for (int nf = 0; nf < 4; ++nf) {
#pragma unroll
        for (int r = 0; r < 4; ++r) {
          int ci = wci + mf * 16 + lhi * 4 + r;
          ob[(size_t)ci * Nn + n0 + nf * 16 + ln] = f2bf(acc[mf][nf][r] + bb[r]);
        }
      }
    }
  }
}

// ---------------- MFMA flash attention, split-KV (S=4), swapped-QK in-lane softmax ----------------
__global__ __launch_bounds__(256) void k_attn_split(
    const ushort_t* __restrict__ theta_b, const ushort_t* __restrict__ phi_b,
    const ushort_t* __restrict__ g_b, ushort_t* __restrict__ ypart,
    float* __restrict__ mpart, float* __restrict__ lpart) {
  __shared__ __align__(16) ushort_t lphi[64 * 128];   // [m][d], swz ^((m&7)<<4)
  __shared__ __align__(16) ushort_t lg[128 * 64];     // [d][m], swz ^((d&7)<<4)
  __shared__ __align__(16) ushort_t lP[4][16 * 64];   // per-wave [q][m], swz ^((q&7)<<4)

  const int tid = threadIdx.x;
  const int lane = tid & 63, w = tid >> 6;
  const int ln = lane & 15, lhi = lane >> 4;

  const int bid = blockIdx.x;
  const int xcd = bid & 7, idx = bid >> 3;       // idx 0..127
  const int pair = xcd * 2 + (idx >> 6);         // 0..15
  const int b = pair >> 2, s = pair & 3;
  const int n0 = (idx & 63) * 64;
  const int kv0 = s * 1024;

  bfrag qf[4];
  {
    const ushort_t* thp =
        theta_b + ((size_t)(b * Nn + n0 + w * 16 + ln)) * CIn + 8 * lhi;
#pragma unroll
    for (int kb = 0; kb < 4; ++kb) qf[kb] = *(const bfrag*)(thp + kb * 32);
  }

  f32x4 yacc[8];
#pragma unroll
  for (int df = 0; df < 8; ++df) yacc[df] = (f32x4){0.f, 0.f, 0.f, 0.f};
  float mq = -3e38f, lq = 0.f;         // per-lane state for q = ln

  const ushort_t* gphi[4];
  const ushort_t* gg[4];
  ushort_t* ldphi[4];
  ushort_t* ldg[4];
#pragma unroll
  for (int k = 0; k < 4; ++k) {
    int ch = w * 4 + k;
    int boff = ch * 1024 + lane * 16;
    {
      int m = boff >> 8, c = (boff >> 4) & 15, cp = c ^ (m & 7);
      gphi[k] = phi_b + (size_t)b * Nn * CIn + (size_t)(kv0 + m) * CIn + cp * 8;
      ldphi[k] = lphi + ch * 512;
    }
    {
      int d = boff >> 7, c = (boff >> 4) & 7, cp = c ^ (d & 7);
      gg[k] = g_b + (size_t)b * CIn * Nn + (size_t)d * Nn + kv0 + cp * 8;
      ldg[k] = lg + ch * 512;
    }
  }
#pragma unroll
  for (int k = 0; k < 4; ++k) {        // prologue: tile 0
    gl_lds16(gphi[k], ldphi[k]);
    gl_lds16(gg[k], ldg[k]);
  }

  ushort_t* lPw = lP[w];

  for (int t = 0; t < 16; ++t) {
    __syncthreads();                   // drains vmcnt -> tile t ready in LDS

    // ---- S^T = phi · theta^T : per lane S[m=nf*16+lhi*4+r][q=ln] ----
    f32x4 sacc[4];
#pragma unroll
    for (int nf = 0; nf < 4; ++nf) sacc[nf] = (f32x4){0.f, 0.f, 0.f, 0.f};
    __builtin_amdgcn_s_setprio(1);
#pragma unroll
    for (int kb = 0; kb < 4; ++kb) {
#pragma unroll
      for (int nf = 0; nf < 4; ++nf) {
        int row = nf * 16 + ln;
        int off = ((row * 128 + kb * 32 + 8 * lhi) * 2) ^ ((ln & 7) << 4);
        bfrag pf = *(const bfrag*)((const char*)lphi + off);
        sacc[nf] = __builtin_amdgcn_mfma_f32_16x16x32_bf16(pf, qf[kb], sacc[nf], 0, 0, 0);
      }
    }
    __builtin_amdgcn_s_setprio(0);

    // ---- in-lane online softmax (one q per lane) ----
    float mx;
    {
      float a0 = fmaxf(fmaxf(sacc[0][0], sacc[0][1]), fmaxf(sacc[0][2], sacc[0][3]));
      float a1 = fmaxf(fmaxf(sacc[1][0], sacc[1][1]), fmaxf(sacc[1][2], sacc[1][3]));
      float a2 = fmaxf(fmaxf(sacc[2][0], sacc[2][1]), fmaxf(sacc[2][2], sacc[2][3]));
      float a3 = fmaxf(fmaxf(sacc[3][0], sacc[3][1]), fmaxf(sacc[3][2], sacc[3][3]));
      mx = fmaxf(fmaxf(a0, a1), fmaxf(a2, a3));
    }
    mx = fmaxf(mx, __shfl_xor(mx, 16));
    mx = fmaxf(mx, __shfl_xor(mx, 32));
    float nm = fmaxf(mq, mx);
    float aaq = __expf(mq - nm);
    mq = nm;

    float psum = 0.f;
#pragma unroll
    for (int nf = 0; nf < 4; ++nf) {
      float p0 = __expf(sacc[nf][0] - nm);
      float p1 = __expf(sacc[nf][1] - nm);
      float p2 = __expf(sacc[nf][2] - nm);
      float p3 = __expf(sacc[nf][3] - nm);
      psum += (p0 + p1) + (p2 + p3);
      uint2 pk;
      pk.x = cvt_pk_bf16(p0, p1);
      pk.y = cvt_pk_bf16(p2, p3);
      int off = ((ln * 64 + nf * 16 + lhi * 4) * 2) ^ ((ln & 7) << 4);
      *(uint2*)((char*)lPw + off) = pk;       // ds_write_b64
    }
    psum += __shfl_xor(psum, 16);
    psum += __shfl_xor(psum, 32);
    lq = lq * aaq + psum;

    float aar[4];
#pragma unroll
    for (int r = 0; r < 4; ++r) aar[r] = __shfl(aaq, 4 * lhi + r);
#pragma unroll
    for (int df = 0; df < 8; ++df)
#pragma unroll
      for (int r = 0; r < 4; ++r) yacc[df][r] *= aar[r];

    // ---- y += P · g^T(rows=d) ----
    __builtin_amdgcn_s_setprio(1);
#pragma unroll
    for (int kb2 = 0; kb2 < 2; ++kb2) {
      int offa = ((ln * 64 + kb2 * 32 + 8 * lhi) * 2) ^ ((ln & 7) << 4);
      bfrag pa = *(const bfrag*)((const char*)lPw + offa);
#pragma unroll
      for (int df = 0; df < 8; ++df) {
        int d = df * 16 + ln;
        int offb = ((d * 64 + kb2 * 32 + 8 * lhi) * 2) ^ ((ln & 7) << 4);
        bfrag gbf = *(const bfrag*)((const char*)lg + offb);
        yacc[df] = __builtin_amdgcn_mfma_f32_16x16x32_bf16(pa, gbf, yacc[df], 0, 0, 0);
      }
    }
    __builtin_amdgcn_s_setprio(0);

    __syncthreads();                   // all waves done reading lphi/lg
    if (t < 15) {
#pragma unroll
      for (int k = 0; k < 4; ++k) {
        gphi[k] += 64 * CIn;
        gg[k] += 64;
        gl_lds16(gphi[k], ldphi[k]);
        gl_lds16(gg[k], ldg[k]);
      }
    }
  }

  // ---- epilogue: stage raw yacc in LDS, then coalesced 16B stores ----
  {
    ushort_t* ly = lphi;               // [64 q][128 d] u16, swz ^((q&7)<<4)
#pragma unroll
    for (int df = 0; df < 8; ++df) {
#pragma unroll
      for (int r = 0; r < 4; ++r) {
        int q = w * 16 + lhi * 4 + r;
        int off = ((q * 128 + df * 16 + ln) * 2) ^ ((q & 7) << 4);
        *(ushort_t*)((char*)ly + off) = f2bf(yacc[df][r]);
      }
    }
  }
  __syncthreads();
  {
    int q = tid >> 2, c0 = (tid & 3) * 32;
    ushort_t* yp = ypart + ((size_t)((b * 4 + s) * Nn + n0 + q)) * CIn + c0;
#pragma unroll
    for (int k = 0; k < 4; ++k) {
      int off = ((q * 128 + c0 + k * 8) * 2) ^ ((q & 7) << 4);
      uint4 v = *(const uint4*)((const char*)lphi + off);
      *(uint4*)(yp + k * 8) = v;
    }
  }
  if (lhi == 0) {                      // lanes 0..15 hold q=ln state
    size_t qi = (size_t)(b * 4 + s) * Nn + n0 + w * 16 + ln;
    mpart[qi] = mq;
    lpart[qi] = lq;
  }
}

// ---------------- final 1x1 via MFMA (+ fused split-merge + GN2 partials); bf16 out ----------------
__global__ __launch_bounds__(512) void k_wconv_mfma(
    const ushort_t* __restrict__ ypart, const float* __restrict__ mpart,
    const float* __restrict__ lpart, const ushort_t* __restrict__ wwb,
    const float* __restrict__ wb, ushort_t* __restrict__ wy_b,
    float* __restrict__ part) {
  __shared__ __align__(16) ushort_t lyt[64 * 128];   // [n][ci], swz ^((n&7)<<4)
  __shared__ float fSc[4][64];
  const int tid = threadIdx.x;
  const int lane = tid & 63, w = tid >> 6;
  const int ln = lane & 15, lhi = lane >> 4;
  const int n0 = blockIdx.x * 64, b = blockIdx.y;
  const int wco = w * 32;

  if (tid < 64) {
    int n = n0 + tid;
    float m0 = mpart[(size_t)(b * 4 + 0) * Nn + n], l0 = lpart[(size_t)(b * 4 + 0) * Nn + n];
    float m1 = mpart[(size_t)(b * 4 + 1) * Nn + n], l1 = lpart[(size_t)(b * 4 + 1) * Nn + n];
    float m2 = mpart[(size_t)(b * 4 + 2) * Nn + n], l2 = lpart[(size_t)(b * 4 + 2) * Nn + n];
    float m3 = mpart[(size_t)(b * 4 + 3) * Nn + n], l3 = lpart[(size_t)(b * 4 + 3) * Nn + n];
    float M = fmaxf(fmaxf(m0, m1), fmaxf(m2, m3));
    float s0 = __expf(m0 - M), s1 = __expf(m1 - M), s2 = __expf(m2 - M), s3 = __expf(m3 - M);
    float inv = 1.f / (s0 * l0 + s1 * l1 + s2 * l2 + s3 * l3);
    fSc[0][tid] = s0 * inv;
    fSc[1][tid] = s1 * inv;
    fSc[2][tid] = s2 * inv;
    fSc[3][tid] = s3 * inv;
  }
  __syncthreads();

  for (int i = tid; i < 1024; i += 512) {
    int n = i >> 4, ch = (i & 15) * 8;
    float f0 = fSc[0][n], f1 = fSc[1][n], f2 = fSc[2][n], f3 = fSc[3][n];
    const ushort_t* yb = ypart + ((size_t)(b * 4) * Nn + n0 + n) * CIn + ch;
    const size_t sstr = (size_t)Nn * CIn;
    u16x8 v0 = *(const u16x8*)(yb);
    u16x8 v1 = *(const u16x8*)(yb + sstr);
    u16x8 v2 = *(const u16x8*)(yb + 2 * sstr);
    u16x8 v3 = *(const u16x8*)(yb + 3 * sstr);
    float a[8];
#pragma unroll
    for (int j = 0; j < 8; ++j)
      a[j] = f0 * bf2f(v0[j]) + f1 * bf2f(v1[j]) + f2 * bf2f(v2[j]) + f3 * bf2f(v3[j]);
    uint4 pk;
    pk.x = cvt_pk_bf16(a[0], a[1]);
    pk.y = cvt_pk_bf16(a[2], a[3]);
    pk.z = cvt_pk_bf16(a[4], a[5]);
    pk.w = cvt_pk_bf16(a[6], a[7]);
    int off = ((n * 128 + ch) * 2) ^ ((n & 7) << 4);
    *(uint4*)((char*)lyt + off) = pk;
  }
  __syncthreads();

  f32x4 acc[2][4];
#pragma unroll
  for (int mf = 0; mf < 2; ++mf)
#pragma unroll
    for (int nf = 0; nf < 4; ++nf) acc[mf][nf] = (f32x4){0.f, 0.f, 0.f, 0.f};

#pragma unroll
  for (int kb = 0; kb < 4; ++kb) {
    const ushort_t* ap = wwb + (size_t)(wco + ln) * CIn + kb * 32 + lhi * 8;
    bfrag af0 = *(const bfrag*)ap;
    bfrag af1 = *(const bfrag*)(ap + 16 * CIn);
    __builtin_amdgcn_s_setprio(1);
#pragma unroll
    for (int nf = 0; nf < 4; ++nf) {
      int n = nf * 16 + ln;
      int off = ((n * 128 + kb * 32 + lhi * 8) * 2) ^ ((n & 7) << 4);
      bfrag bf = *(const bfrag*)((const char*)lyt + off);
      acc[0][nf] = __builtin_amdgcn_mfma_f32_16x16x32_bf16(af0, bf, acc[0][nf], 0, 0, 0);
      acc[1][nf] = __builtin_amdgcn_mfma_f32_16x16x32_bf16(af1, bf, acc[1][nf], 0, 0, 0);
    }
    __builtin_amdgcn_s_setprio(0);
  }

  float s_ = 0.f, q_ = 0.f;
#pragma unroll
  for (int mf = 0; mf < 2; ++mf) {
    float4 bv = *(const float4*)(wb + wco + mf * 16 + lhi * 4);
    float bb[4] = {bv.x, bv.y, bv.z, bv.w};
#pragma unroll
    for (int nf = 0; nf < 4; ++nf) {
#pragma unroll
      for (int r = 0; r < 4; ++r) {
        int co = wco + mf * 16 + lhi * 4 + r;
        float v = acc[mf][nf][r] + bb[r];
        wy_b[((size_t)(b * Cn + co)) * Nn + n0 + nf * 16 + ln] = f2bf(v);
        s_ += v;
        q_ += v * v;
      }
    }
  }
#pragma unroll
  for (int off = 32; off; off >>= 1) {
    s_ += __shfl_xor(s_, off);
    q_ += __shfl_xor(q_, off);
  }
  if (lane == 0) {
    size_t pi = ((size_t)(b * Gn + w) * 64 + blockIdx.x) * 2;
    part[pi] = s_;
    part[pi + 1] = q_;
  }
}

// ---------------- final: out = GN2(wy)*0.1 + xs ----------------
__global__ __launch_bounds__(256) void k_final(
    const ushort_t* __restrict__ wy_b, const float* __restrict__ stats,
    const float* __restrict__ g2w, const float* __restrict__ g2b,
    const ushort_t* __restrict__ xs_b, float* __restrict__ out) {
  size_t i = ((size_t)blockIdx.x * 256 + threadIdx.x) * 8;
  int c = (int)((i >> 12) & 255);
  int bg = (int)(i >> 20) * Gn + (c >> 5);
  float mean = stats[bg * 2], rstd = stats[bg * 2 + 1];
  float sc = g2w[c] * rstd * 0.1f;
  float sb = (g2b[c] - mean * rstd * g2w[c]) * 0.1f;
  u16x8 wv = *(const u16x8*)(wy_b + i);
  u16x8 xv = *(const u16x8*)(xs_b + i);
  float4 o0, o1;
  o0.x = bf2f(wv[0]) * sc + sb + bf2f(xv[0]);
  o0.y = bf2f(wv[1]) * sc + sb + bf2f(xv[1]);
  o0.z = bf2f(wv[2]) * sc + sb + bf2f(xv[2]);
  o0.w = bf2f(wv[3]) * sc + sb + bf2f(xv[3]);
  o1.x = bf2f(wv[4]) * sc + sb + bf2f(xv[4]);
  o1.y = bf2f(wv[5]) * sc + sb + bf2f(xv[5]);
  o1.z = bf2f(wv[6]) * sc + sb + bf2f(xv[6]);
  o1.w = bf2f(wv[7]) * sc + sb + bf2f(xv[7]);
  *(float4*)(out + i) = o0;
  *(float4*)(out + i + 4) = o1;
}

extern "C" void kernel_launch(void* const* d_in, const int* in_sizes, int n_in,
                              void* d_out, int out_size, void* d_ws, size_t ws_size,
                              hipStream_t stream) {
  (void)in_sizes; (void)n_in; (void)out_size; (void)ws_size;
  const float* x   = (const float*)d_in[0];
  const float* sw  = (const float*)d_in[1];
  const float* sb  = (const float*)d_in[2];
  const float* g1w = (const float*)d_in[3];
  const float* g1b = (const float*)d_in[4];
  const float* gw  = (const float*)d_in[5];
  const float* gb  = (const float*)d_in[6];
  const float* thw = (const float*)d_in[7];
  const float* thb = (const float*)d_in[8];
  const float* phw = (const float*)d_in[9];
  const float* phb = (const float*)d_in[10];
  const float* ww  = (const float*)d_in[11];
  const float* wb  = (const float*)d_in[12];
  const float* g2w = (const float*)d_in[13];
  const float* g2b = (const float*)d_in[14];
  float* out = (float*)d_out;
  float* ws = (float*)d_ws;

  // layout (float offsets). R1 proved ws >= 16,778,368 f; high-water = 16,225,536 f.
  ushort_t* xr_b    = (ushort_t*)ws;                   // [B][C][N] u16 (head of region 0)
  ushort_t* ypart   = (ushort_t*)ws;                   // [B*4][N][Ci] u16 (xr_b dead by attn)
  ushort_t* xs_b    = (ushort_t*)(ws + 4194304);       // [B][C][N] u16
  ushort_t* xbT     = (ushort_t*)(ws + 6291456);       // [B][HW][C] u16 (dead after conv)
  ushort_t* theta_b = (ushort_t*)(ws + 10486912);      // dead after attn
  ushort_t* phi_b   = (ushort_t*)(ws + 11535488);
  ushort_t* g_b     = (ushort_t*)(ws + 12584064);
  ushort_t* xsT     = (ushort_t*)(ws + 13632640);      // dead after proj
  ushort_t* w9      = (ushort_t*)(ws + 15729792);
  ushort_t* wp9     = (ushort_t*)(ws + 16024704);
  ushort_t* wwb     = (ushort_t*)(ws + 16073856);      // ends 16090240 f
  ushort_t* wy_b    = (ushort_t*)(ws + 10486912);      // overlays dead theta+phi
  float*    mpart   = ws + 16090240;                   // 65536 f
  float*    lpart   = ws + 16155776;                   // 65536 f
  float*    part    = ws + 16221312;                   // 4096 f
  float*    st1     = ws + 16225408;                   // 64 f
  float*    st2     = ws + 16225472;                   // 64 f

  k_prepack<<<2816, 256, 0, stream>>>(sw, thw, phw, gw, ww, w9, wp9, wwb);
  k_xT<<<dim3(64, 8, 4), 256, 0, stream>>>(x, xbT);
  k_conv_mfma<<<dim3(Hn, Bn), 512, 0, stream>>>(xbT, w9, sb, xr_b, part);
  k_gn_final<<<1, 64, 0, stream>>>(part, st1);
  k_gn1_apply_t<<<dim3(64, 8, 4), 256, 0, stream>>>(xr_b, st1, g1w, g1b, xs_b, xsT);
  k_proj_mfma<<<dim3(64, 3, 4), 256, 0, stream>>>(xsT, wp9, thb, phb, gb,
                                                  theta_b, phi_b, g_b);
  k_attn_split<<<1024, 256, 0, stream>>>(theta_b, phi_b, g_b, ypart, mpart, lpart);
  k_wconv_mfma<<<dim3(64, 4), 512, 0, stream>>>(ypart, mpart, lpart, wwb, wb, wy_b, part);
  k_gn_final<<<1, 64, 0, stream>>>(part, st2);
  k_final<<<2048, 256, 0, stream>>>(wy_b, st2, g2w, g2b, xs_b, out);
}

// Round 16
// 158.384 us; speedup vs baseline: 1.0222x; 1.0222x over previous
//
#include <hip/hip_runtime.h>
#include <math.h>

#define Bn 4
#define Cn 256
#define CIn 128
#define Hn 64
#define Wn 64
#define Nn 4096
#define Gn 8
#define CPGn 32
#define EPSc 1e-5f

typedef unsigned short ushort_t;
typedef short bfrag __attribute__((ext_vector_type(8)));       // 8 bf16 (4 VGPRs)
typedef float f32x4 __attribute__((ext_vector_type(4)));
typedef ushort_t u16x8 __attribute__((ext_vector_type(8)));

static __device__ __forceinline__ ushort_t f2bf(float f) {
  unsigned u = __float_as_uint(f);
  return (ushort_t)((u + 0x7FFFu + ((u >> 16) & 1u)) >> 16);   // RNE
}

static __device__ __forceinline__ unsigned cvt_pk_bf16(float lo, float hi) {
  unsigned r;
  asm("v_cvt_pk_bf16_f32 %0, %1, %2" : "=v"(r) : "v"(lo), "v"(hi));
  return r;
}

static __device__ __forceinline__ float bf2f(ushort_t u) {
  return __uint_as_float((unsigned)u << 16);
}

// async global->LDS, 16B per lane; dest = uniform base + lane*16 (HW rule)
static __device__ __forceinline__ void gl_lds16(const ushort_t* g, ushort_t* l) {
  __builtin_amdgcn_global_load_lds(
      (__attribute__((address_space(1))) void*)g,
      (__attribute__((address_space(3))) void*)l, 16, 0, 0);
}

// in-block GN stats: reduce 64 partials of group bg (same order as old k_gn_final)
static __device__ __forceinline__ void gn_stats(
    const float* __restrict__ part, int bg, float* sst, int tid) {
  if (tid == 0) {
    float s = 0.f, ss = 0.f;
    for (int j = 0; j < 64; ++j) {
      s += part[(bg * 64 + j) * 2];
      ss += part[(bg * 64 + j) * 2 + 1];
    }
    const float inv = 1.f / (float)(CPGn * Nn);
    float mean = s * inv;
    float var = ss * inv - mean * mean;
    sst[0] = mean;
    sst[1] = rsqrtf(var + EPSc);
  }
}

// ---------------- weight prepack (fp32 -> bf16, rearranged) ----------------
__global__ __launch_bounds__(256) void k_prepack(
    const float* __restrict__ w3, const float* __restrict__ thw,
    const float* __restrict__ phw, const float* __restrict__ gww,
    const float* __restrict__ ww,
    ushort_t* __restrict__ w9, ushort_t* __restrict__ wp9,
    ushort_t* __restrict__ wwb) {
  int i = blockIdx.x * 256 + threadIdx.x;
  if (i < 589824) {
    float v = w3[i];
    int co = i / 2304, r = i % 2304, ci = r / 9, tap = r % 9;
    w9[tap * 65536 + co * 256 + ci] = f2bf(v);
  } else if (i < 688128) {
    int j = i - 589824;
    int which = j >> 15, r = j & 32767;
    const float* src = (which == 0) ? thw : (which == 1) ? phw : gww;
    wp9[j] = f2bf(src[r]);
  } else if (i < 720896) {
    int j = i - 688128;
    wwb[j] = f2bf(ww[j]);
  }
}

// ---------------- x transpose: x[b][c][h][w] fp32 -> xbT[b][hw][c] bf16 ----------------
__global__ __launch_bounds__(256) void k_xT(
    const float* __restrict__ x, ushort_t* __restrict__ xbT) {
  __shared__ ushort_t lt[32 * 64];
  const int t = threadIdx.x;
  const int n0 = blockIdx.x * 64, c0 = blockIdx.y * 32, b = blockIdx.z;
#pragma unroll
  for (int p = 0; p < 8; ++p) {
    int c = c0 + p * 4 + (t >> 6);
    int n = n0 + (t & 63);
    lt[(c - c0) * 64 + (t & 63)] = f2bf(x[((size_t)(b * Cn + c)) * Nn + n]);
  }
  __syncthreads();
  {
    int n = t >> 2, cg = t & 3;
    u16x8 pk;
#pragma unroll
    for (int j = 0; j < 8; ++j) pk[j] = lt[(cg * 8 + j) * 64 + n];
    *(u16x8*)(xbT + ((size_t)(b * Nn + n0 + n)) * Cn + c0 + cg * 8) = pk;
  }
}

// ---------------- conv3x3 via implicit-GEMM MFMA (+ fused GN1 partials) ----------------
__global__ __launch_bounds__(512) void k_conv_mfma(
    const ushort_t* __restrict__ xbT, const ushort_t* __restrict__ w9,
    const float* __restrict__ b3, ushort_t* __restrict__ xr_b,
    float* __restrict__ part) {
  __shared__ __align__(16) ushort_t lx[3 * 66 * 128];   // [dh][wp][ci], byte swz ^((wp&7)<<4)
  const int tid = threadIdx.x;
  const int lane = tid & 63, w = tid >> 6;
  const int ln = lane & 15, lhi = lane >> 4;
  const int h = blockIdx.x, b = blockIdx.y;
  const int wco = w * 32;

  // zero pad columns (wp = 0, 65) once
  for (int i = tid; i < 768; i += 512) {
    int dh = i / 256, r = i % 256, wpz = (r >> 7) ? 65 : 0, ci = r & 127;
    int off = (((dh * 66 + wpz) * 128 + ci) * 2) ^ ((wpz & 7) << 4);
    *(ushort_t*)((char*)lx + off) = 0;
  }

  f32x4 acc[2][4];
#pragma unroll
  for (int mf = 0; mf < 2; ++mf)
#pragma unroll
    for (int nf = 0; nf < 4; ++nf) acc[mf][nf] = (f32x4){0.f, 0.f, 0.f, 0.f};

  for (int cc = 0; cc < 2; ++cc) {
    __syncthreads();                     // prior reads (and pad writes) done
#pragma unroll
    for (int k = 0; k < 6; ++k) {
      int ch = w * 6 + k;                // 0..47 = 3 dh x 16
      int dh = ch >> 4, wq = (ch & 15) * 4;
      int rowl = wq + (lane >> 4);       // (wp-1) in 0..63
      int wp = rowl + 1;
      int hh = h + dh - 1;
      ushort_t* dst = lx + (dh * 66 + wq + 1) * 128;
      if (hh >= 0 && hh < Hn) {
        int srcC = (((lane & 15) ^ (wp & 7)) * 8) + cc * 128;
        gl_lds16(xbT + ((size_t)(b * Nn + hh * Wn + rowl)) * Cn + srcC, dst);
      } else {
        *(uint4*)((char*)lx + (((dh * 66 + wq + 1) * 128 + lane * 8) * 2)) =
            (uint4){0u, 0u, 0u, 0u};
      }
    }
    __syncthreads();                     // drains vmcnt -> tile ready

#pragma unroll
    for (int tap = 0; tap < 9; ++tap) {
      const int dh = tap / 3, dw = tap % 3;
#pragma unroll
      for (int kb = 0; kb < 4; ++kb) {
        const ushort_t* ap = w9 + tap * 65536 + (size_t)(wco + ln) * 256 +
                             cc * 128 + kb * 32 + lhi * 8;
        bfrag af0 = *(const bfrag*)ap;
        bfrag af1 = *(const bfrag*)(ap + 16 * 256);
        __builtin_amdgcn_s_setprio(1);
#pragma unroll
        for (int nf = 0; nf < 4; ++nf) {
          int wp = nf * 16 + ln + dw;
          int off = (((dh * 66 + wp) * 128 + kb * 32 + lhi * 8) * 2) ^ ((wp & 7) << 4);
          bfrag bf = *(const bfrag*)((const char*)lx + off);
          acc[0][nf] = __builtin_amdgcn_mfma_f32_16x16x32_bf16(af0, bf, acc[0][nf], 0, 0, 0);
          acc[1][nf] = __builtin_amdgcn_mfma_f32_16x16x32_bf16(af1, bf, acc[1][nf], 0, 0, 0);
        }
        __builtin_amdgcn_s_setprio(0);
      }
    }
  }

  // epilogue + fused GN1 partials (wave w == channel group w); bf16 out
  float s_ = 0.f, q_ = 0.f;
#pragma unroll
  for (int mf = 0; mf < 2; ++mf) {
    float4 bv = *(const float4*)(b3 + wco + mf * 16 + lhi * 4);
    float bb[4] = {bv.x, bv.y, bv.z, bv.w};
#pragma unroll
    for (int nf = 0; nf < 4; ++nf) {
#pragma unroll
      for (int r = 0; r < 4; ++r) {
        int co = wco + mf * 16 + lhi * 4 + r;
        float v = acc[mf][nf][r] + bb[r];
        xr_b[((size_t)(b * Cn + co)) * Nn + h * Wn + nf * 16 + ln] = f2bf(v);
        s_ += v;
        q_ += v * v;
      }
    }
  }
#pragma unroll
  for (int off = 32; off; off >>= 1) {
    s_ += __shfl_xor(s_, off);
    q_ += __shfl_xor(q_, off);
  }
  if (lane == 0) {
    size_t pi = ((size_t)(b * Gn + w) * 64 + h) * 2;
    part[pi] = s_;
    part[pi + 1] = q_;
  }
}

// ---------------- GN1 apply + ReLU (stats computed in-block from partials) ----------------
__global__ __launch_bounds__(256) void k_gn1_apply_t(
    const ushort_t* __restrict__ xr_b, const float* __restrict__ part,
    const float* __restrict__ gw, const float* __restrict__ gb,
    ushort_t* __restrict__ xs_b, ushort_t* __restrict__ xsT) {
  __shared__ ushort_t lt[32 * 64];
  __shared__ float sst[2];
  const int t = threadIdx.x;
  const int n0 = blockIdx.x * 64, c0 = blockIdx.y * 32, b = blockIdx.z;
  gn_stats(part, b * Gn + blockIdx.y, sst, t);
  __syncthreads();
  {
    int c = c0 + (t >> 3);
    int nc = (t & 7) * 8;
    float mean = sst[0], rstd = sst[1];
    float sc = gw[c] * rstd;
    float sb = gb[c] - mean * sc;
    size_t idx = ((size_t)(b * Cn + c)) * Nn + n0 + nc;
    u16x8 v = *(const u16x8*)(xr_b + idx);
    u16x8 o;
#pragma unroll
    for (int j = 0; j < 8; ++j)
      o[j] = f2bf(fmaxf(bf2f(v[j]) * sc + sb, 0.f));
    *(u16x8*)(xs_b + idx) = o;
#pragma unroll
    for (int j = 0; j < 8; ++j) lt[(c - c0) * 64 + nc + j] = o[j];
  }
  __syncthreads();
  {
    int n = t >> 2, cg = t & 3;
    u16x8 pk;
#pragma unroll
    for (int j = 0; j < 8; ++j) pk[j] = lt[(cg * 8 + j) * 64 + n];
    *(u16x8*)(xsT + ((size_t)(b * Nn + n0 + n)) * Cn + c0 + cg * 8) = pk;
  }
}

// ---------------- projections via MFMA ----------------
__global__ __launch_bounds__(256) void k_proj_mfma(
    const ushort_t* __restrict__ xsT, const ushort_t* __restrict__ wp9,
    const float* __restrict__ thb, const float* __restrict__ phb,
    const float* __restrict__ gbb,
    ushort_t* __restrict__ theta_b, ushort_t* __restrict__ phi_b,
    ushort_t* __restrict__ g_b) {
  __shared__ __align__(16) ushort_t lxs[64 * 256];   // [n][c], swz ^((n&7)<<4)
  const int tid = threadIdx.x;
  const int lane = tid & 63, w = tid >> 6;
  const int ln = lane & 15, lhi = lane >> 4;
  const int n0 = blockIdx.x * 64, which = blockIdx.y, b = blockIdx.z;
  const int wci = w * 32;

  for (int i = tid; i < 2048; i += 256) {
    int n = i >> 5, cchunk = (i & 31) * 8;
    uint4 v = *(const uint4*)(xsT + ((size_t)(b * Nn + n0 + n)) * Cn + cchunk);
    int off = ((n * 256 + cchunk) * 2) ^ ((n & 7) << 4);
    *(uint4*)((char*)lxs + off) = v;
  }
  __syncthreads();

  f32x4 acc[2][4];
#pragma unroll
  for (int mf = 0; mf < 2; ++mf)
#pragma unroll
    for (int nf = 0; nf < 4; ++nf) acc[mf][nf] = (f32x4){0.f, 0.f, 0.f, 0.f};

#pragma unroll
  for (int kb = 0; kb < 8; ++kb) {
    const ushort_t* ap = wp9 + which * 32768 + (size_t)(wci + ln) * 256 + kb * 32 + lhi * 8;
    bfrag af0 = *(const bfrag*)ap;
    bfrag af1 = *(const bfrag*)(ap + 16 * 256);
    __builtin_amdgcn_s_setprio(1);
#pragma unroll
    for (int nf = 0; nf < 4; ++nf) {
      int n = nf * 16 + ln;
      int off = ((n * 256 + kb * 32 + lhi * 8) * 2) ^ ((n & 7) << 4);
      bfrag bf = *(const bfrag*)((const char*)lxs + off);
      acc[0][nf] = __builtin_amdgcn_mfma_f32_16x16x32_bf16(af0, bf, acc[0][nf], 0, 0, 0);
      acc[1][nf] = __builtin_amdgcn_mfma_f32_16x16x32_bf16(af1, bf, acc[1][nf], 0, 0, 0);
    }
    __builtin_amdgcn_s_setprio(0);
  }

  const float* bs = (which == 0) ? thb : (which == 1) ? phb : gbb;
#pragma unroll
  for (int mf = 0; mf < 2; ++mf) {
    float4 bv = *(const float4*)(bs + wci + mf * 16 + lhi * 4);
    float bb[4] = {bv.x, bv.y, bv.z, bv.w};
    if (which < 2) {
      ushort_t* ob = ((which == 0) ? theta_b : phi_b) + (size_t)b * Nn * CIn;
#pragma unroll
      for (int nf = 0; nf < 4; ++nf) {
        int n = n0 + nf * 16 + ln;
        unsigned lo = (unsigned)f2bf(acc[mf][nf][0] + bb[0]) |
                      ((unsigned)f2bf(acc[mf][nf][1] + bb[1]) << 16);
        unsigned hi = (unsigned)f2bf(acc[mf][nf][2] + bb[2]) |
                      ((unsigned)f2bf(acc[mf][nf][3] + bb[3]) << 16);
        ushort_t* base = ob + (size_t)n * CIn + wci + mf * 16 + lhi * 4;
        *(unsigned*)base = lo;
        *(unsigned*)(base + 2) = hi;
      }
    } else {
      ushort_t* ob = g_b + (size_t)b * CIn * Nn;
#pragma unroll
      for (int nf = 0; nf < 4; ++nf) {
#pragma unroll
        for (int r = 0; r < 4; ++r) {
          int ci = wci + mf * 16 + lhi * 4 + r;
          ob[(size_t)ci * Nn + n0 + nf * 16 + ln] = f2bf(acc[mf][nf][r] + bb[r]);
        }
      }
    }
  }
}

// ---------------- MFMA flash attention, split-KV (S=4), swapped-QK in-lane softmax ----------------
__global__ __launch_bounds__(256) void k_attn_split(
    const ushort_t* __restrict__ theta_b, const ushort_t* __restrict__ phi_b,
    const ushort_t* __restrict__ g_b, ushort_t* __restrict__ ypart,
    float* __restrict__ mpart, float* __restrict__ lpart) {
  __shared__ __align__(16) ushort_t lphi[64 * 128];   // [m][d], swz ^((m&7)<<4)
  __shared__ __align__(16) ushort_t lg[128 * 64];     // [d][m], swz ^((d&7)<<4)
  __shared__ __align__(16) ushort_t lP[4][16 * 64];   // per-wave [q][m], swz ^((q&7)<<4)

  const int tid = threadIdx.x;
  const int lane = tid & 63, w = tid >> 6;
  const int ln = lane & 15, lhi = lane >> 4;

  const int bid = blockIdx.x;
  const int xcd = bid & 7, idx = bid >> 3;       // idx 0..127
  const int pair = xcd * 2 + (idx >> 6);         // 0..15
  const int b = pair >> 2, s = pair & 3;
  const int n0 = (idx & 63) * 64;
  const int kv0 = s * 1024;

  bfrag qf[4];
  {
    const ushort_t* thp =
        theta_b + ((size_t)(b * Nn + n0 + w * 16 + ln)) * CIn + 8 * lhi;
#pragma unroll
    for (int kb = 0; kb < 4; ++kb) qf[kb] = *(const bfrag*)(thp + kb * 32);
  }

  f32x4 yacc[8];
#pragma unroll
  for (int df = 0; df < 8; ++df) yacc[df] = (f32x4){0.f, 0.f, 0.f, 0.f};
  float mq = -3e38f, lq = 0.f;         // per-lane state for q = ln

  const ushort_t* gphi[4];
  const ushort_t* gg[4];
  ushort_t* ldphi[4];
  ushort_t* ldg[4];
#pragma unroll
  for (int k = 0; k < 4; ++k) {
    int ch = w * 4 + k;
    int boff = ch * 1024 + lane * 16;
    {
      int m = boff >> 8, c = (boff >> 4) & 15, cp = c ^ (m & 7);
      gphi[k] = phi_b + (size_t)b * Nn * CIn + (size_t)(kv0 + m) * CIn + cp * 8;
      ldphi[k] = lphi + ch * 512;
    }
    {
      int d = boff >> 7, c = (boff >> 4) & 7, cp = c ^ (d & 7);
      gg[k] = g_b + (size_t)b * CIn * Nn + (size_t)d * Nn + kv0 + cp * 8;
      ldg[k] = lg + ch * 512;
    }
  }
#pragma unroll
  for (int k = 0; k < 4; ++k) {        // prologue: tile 0
    gl_lds16(gphi[k], ldphi[k]);
    gl_lds16(gg[k], ldg[k]);
  }

  ushort_t* lPw = lP[w];

  for (int t = 0; t < 16; ++t) {
    __syncthreads();                   // drains vmcnt -> tile t ready in LDS

    // ---- S^T = phi · theta^T : per lane S[m=nf*16+lhi*4+r][q=ln] ----
    f32x4 sacc[4];
#pragma unroll
    for (int nf = 0; nf < 4; ++nf) sacc[nf] = (f32x4){0.f, 0.f, 0.f, 0.f};
    __builtin_amdgcn_s_setprio(1);
#pragma unroll
    for (int kb = 0; kb < 4; ++kb) {
#pragma unroll
      for (int nf = 0; nf < 4; ++nf) {
        int row = nf * 16 + ln;
        int off = ((row * 128 + kb * 32 + 8 * lhi) * 2) ^ ((ln & 7) << 4);
        bfrag pf = *(const bfrag*)((const char*)lphi + off);
        sacc[nf] = __builtin_amdgcn_mfma_f32_16x16x32_bf16(pf, qf[kb], sacc[nf], 0, 0, 0);
      }
    }
    __builtin_amdgcn_s_setprio(0);

    // ---- in-lane online softmax (one q per lane) ----
    float mx;
    {
      float a0 = fmaxf(fmaxf(sacc[0][0], sacc[0][1]), fmaxf(sacc[0][2], sacc[0][3]));
      float a1 = fmaxf(fmaxf(sacc[1][0], sacc[1][1]), fmaxf(sacc[1][2], sacc[1][3]));
      float a2 = fmaxf(fmaxf(sacc[2][0], sacc[2][1]), fmaxf(sacc[2][2], sacc[2][3]));
      float a3 = fmaxf(fmaxf(sacc[3][0], sacc[3][1]), fmaxf(sacc[3][2], sacc[3][3]));
      mx = fmaxf(fmaxf(a0, a1), fmaxf(a2, a3));
    }
    mx = fmaxf(mx, __shfl_xor(mx, 16));
    mx = fmaxf(mx, __shfl_xor(mx, 32));
    float nm = fmaxf(mq, mx);
    float aaq = __expf(mq - nm);
    mq = nm;

    float psum = 0.f;
#pragma unroll
    for (int nf = 0; nf < 4; ++nf) {
      float p0 = __expf(sacc[nf][0] - nm);
      float p1 = __expf(sacc[nf][1] - nm);
      float p2 = __expf(sacc[nf][2] - nm);
      float p3 = __expf(sacc[nf][3] - nm);
      psum += (p0 + p1) + (p2 + p3);
      uint2 pk;
      pk.x = cvt_pk_bf16(p0, p1);
      pk.y = cvt_pk_bf16(p2, p3);
      int off = ((ln * 64 + nf * 16 + lhi * 4) * 2) ^ ((ln & 7) << 4);
      *(uint2*)((char*)lPw + off) = pk;       // ds_write_b64
    }
    psum += __shfl_xor(psum, 16);
    psum += __shfl_xor(psum, 32);
    lq = lq * aaq + psum;

    float aar[4];
#pragma unroll
    for (int r = 0; r < 4; ++r) aar[r] = __shfl(aaq, 4 * lhi + r);
#pragma unroll
    for (int df = 0; df < 8; ++df)
#pragma unroll
      for (int r = 0; r < 4; ++r) yacc[df][r] *= aar[r];

    // ---- y += P · g^T(rows=d) ----
    __builtin_amdgcn_s_setprio(1);
#pragma unroll
    for (int kb2 = 0; kb2 < 2; ++kb2) {
      int offa = ((ln * 64 + kb2 * 32 + 8 * lhi) * 2) ^ ((ln & 7) << 4);
      bfrag pa = *(const bfrag*)((const char*)lPw + offa);
#pragma unroll
      for (int df = 0; df < 8; ++df) {
        int d = df * 16 + ln;
        int offb = ((d * 64 + kb2 * 32 + 8 * lhi) * 2) ^ ((ln & 7) << 4);
        bfrag gbf = *(const bfrag*)((const char*)lg + offb);
        yacc[df] = __builtin_amdgcn_mfma_f32_16x16x32_bf16(pa, gbf, yacc[df], 0, 0, 0);
      }
    }
    __builtin_amdgcn_s_setprio(0);

    __syncthreads();                   // all waves done reading lphi/lg
    if (t < 15) {
#pragma unroll
      for (int k = 0; k < 4; ++k) {
        gphi[k] += 64 * CIn;
        gg[k] += 64;
        gl_lds16(gphi[k], ldphi[k]);
        gl_lds16(gg[k], ldg[k]);
      }
    }
  }

  // ---- epilogue: stage raw yacc in LDS, then coalesced 16B stores ----
  {
    ushort_t* ly = lphi;               // [64 q][128 d] u16, swz ^((q&7)<<4)
#pragma unroll
    for (int df = 0; df < 8; ++df) {
#pragma unroll
      for (int r = 0; r < 4; ++r) {
        int q = w * 16 + lhi * 4 + r;
        int off = ((q * 128 + df * 16 + ln) * 2) ^ ((q & 7) << 4);
        *(ushort_t*)((char*)ly + off) = f2bf(yacc[df][r]);
      }
    }
  }
  __syncthreads();
  {
    int q = tid >> 2, c0 = (tid & 3) * 32;
    ushort_t* yp = ypart + ((size_t)((b * 4 + s) * Nn + n0 + q)) * CIn + c0;
#pragma unroll
    for (int k = 0; k < 4; ++k) {
      int off = ((q * 128 + c0 + k * 8) * 2) ^ ((q & 7) << 4);
      uint4 v = *(const uint4*)((const char*)lphi + off);
      *(uint4*)(yp + k * 8) = v;
    }
  }
  if (lhi == 0) {                      // lanes 0..15 hold q=ln state
    size_t qi = (size_t)(b * 4 + s) * Nn + n0 + w * 16 + ln;
    mpart[qi] = mq;
    lpart[qi] = lq;
  }
}

// ---------------- final 1x1 via MFMA (+ fused split-merge + GN2 partials); bf16 out ----------------
__global__ __launch_bounds__(512) void k_wconv_mfma(
    const ushort_t* __restrict__ ypart, const float* __restrict__ mpart,
    const float* __restrict__ lpart, const ushort_t* __restrict__ wwb,
    const float* __restrict__ wb, ushort_t* __restrict__ wy_b,
    float* __restrict__ part) {
  __shared__ __align__(16) ushort_t lyt[64 * 128];   // [n][ci], swz ^((n&7)<<4)
  __shared__ float fSc[4][64];
  const int tid = threadIdx.x;
  const int lane = tid & 63, w = tid >> 6;
  const int ln = lane & 15, lhi = lane >> 4;
  const int n0 = blockIdx.x * 64, b = blockIdx.y;
  const int wco = w * 32;

  if (tid < 64) {
    int n = n0 + tid;
    float m0 = mpart[(size_t)(b * 4 + 0) * Nn + n], l0 = lpart[(size_t)(b * 4 + 0) * Nn + n];
    float m1 = mpart[(size_t)(b * 4 + 1) * Nn + n], l1 = lpart[(size_t)(b * 4 + 1) * Nn + n];
    float m2 = mpart[(size_t)(b * 4 + 2) * Nn + n], l2 = lpart[(size_t)(b * 4 + 2) * Nn + n];
    float m3 = mpart[(size_t)(b * 4 + 3) * Nn + n], l3 = lpart[(size_t)(b * 4 + 3) * Nn + n];
    float M = fmaxf(fmaxf(m0, m1), fmaxf(m2, m3));
    float s0 = __expf(m0 - M), s1 = __expf(m1 - M), s2 = __expf(m2 - M), s3 = __expf(m3 - M);
    float inv = 1.f / (s0 * l0 + s1 * l1 + s2 * l2 + s3 * l3);
    fSc[0][tid] = s0 * inv;
    fSc[1][tid] = s1 * inv;
    fSc[2][tid] = s2 * inv;
    fSc[3][tid] = s3 * inv;
  }
  __syncthreads();

  for (int i = tid; i < 1024; i += 512) {
    int n = i >> 4, ch = (i & 15) * 8;
    float f0 = fSc[0][n], f1 = fSc[1][n], f2 = fSc[2][n], f3 = fSc[3][n];
    const ushort_t* yb = ypart + ((size_t)(b * 4) * Nn + n0 + n) * CIn + ch;
    const size_t sstr = (size_t)Nn * CIn;
    u16x8 v0 = *(const u16x8*)(yb);
    u16x8 v1 = *(const u16x8*)(yb + sstr);
    u16x8 v2 = *(const u16x8*)(yb + 2 * sstr);
    u16x8 v3 = *(const u16x8*)(yb + 3 * sstr);
    float a[8];
#pragma unroll
    for (int j = 0; j < 8; ++j)
      a[j] = f0 * bf2f(v0[j]) + f1 * bf2f(v1[j]) + f2 * bf2f(v2[j]) + f3 * bf2f(v3[j]);
    uint4 pk;
    pk.x = cvt_pk_bf16(a[0], a[1]);
    pk.y = cvt_pk_bf16(a[2], a[3]);
    pk.z = cvt_pk_bf16(a[4], a[5]);
    pk.w = cvt_pk_bf16(a[6], a[7]);
    int off = ((n * 128 + ch) * 2) ^ ((n & 7) << 4);
    *(uint4*)((char*)lyt + off) = pk;
  }
  __syncthreads();

  f32x4 acc[2][4];
#pragma unroll
  for (int mf = 0; mf < 2; ++mf)
#pragma unroll
    for (int nf = 0; nf < 4; ++nf) acc[mf][nf] = (f32x4){0.f, 0.f, 0.f, 0.f};

#pragma unroll
  for (int kb = 0; kb < 4; ++kb) {
    const ushort_t* ap = wwb + (size_t)(wco + ln) * CIn + kb * 32 + lhi * 8;
    bfrag af0 = *(const bfrag*)ap;
    bfrag af1 = *(const bfrag*)(ap + 16 * CIn);
    __builtin_amdgcn_s_setprio(1);
#pragma unroll
    for (int nf = 0; nf < 4; ++nf) {
      int n = nf * 16 + ln;
      int off = ((n * 128 + kb * 32 + lhi * 8) * 2) ^ ((n & 7) << 4);
      bfrag bf = *(const bfrag*)((const char*)lyt + off);
      acc[0][nf] = __builtin_amdgcn_mfma_f32_16x16x32_bf16(af0, bf, acc[0][nf], 0, 0, 0);
      acc[1][nf] = __builtin_amdgcn_mfma_f32_16x16x32_bf16(af1, bf, acc[1][nf], 0, 0, 0);
    }
    __builtin_amdgcn_s_setprio(0);
  }

  float s_ = 0.f, q_ = 0.f;
#pragma unroll
  for (int mf = 0; mf < 2; ++mf) {
    float4 bv = *(const float4*)(wb + wco + mf * 16 + lhi * 4);
    float bb[4] = {bv.x, bv.y, bv.z, bv.w};
#pragma unroll
    for (int nf = 0; nf < 4; ++nf) {
#pragma unroll
      for (int r = 0; r < 4; ++r) {
        int co = wco + mf * 16 + lhi * 4 + r;
        float v = acc[mf][nf][r] + bb[r];
        wy_b[((size_t)(b * Cn + co)) * Nn + n0 + nf * 16 + ln] = f2bf(v);
        s_ += v;
        q_ += v * v;
      }
    }
  }
#pragma unroll
  for (int off = 32; off; off >>= 1) {
    s_ += __shfl_xor(s_, off);
    q_ += __shfl_xor(q_, off);
  }
  if (lane == 0) {
    size_t pi = ((size_t)(b * Gn + w) * 64 + blockIdx.x) * 2;
    part[pi] = s_;
    part[pi + 1] = q_;
  }
}

// ---------------- final: out = GN2(wy)*0.1 + xs (stats in-block from partials) ----------------
__global__ __launch_bounds__(256) void k_final(
    const ushort_t* __restrict__ wy_b, const float* __restrict__ part,
    const float* __restrict__ g2w, const float* __restrict__ g2b,
    const ushort_t* __restrict__ xs_b, float* __restrict__ out) {
  __shared__ float sst[2];
  const int t = threadIdx.x;
  size_t base = (size_t)blockIdx.x * 2048;           // block spans one (b, c)
  int cb = (int)((base >> 12) & 255);
  int bb = (int)(base >> 20);
  gn_stats(part, bb * Gn + (cb >> 5), sst, t);
  __syncthreads();
  size_t i = base + (size_t)t * 8;
  int c = (int)((i >> 12) & 255);
  float mean = sst[0], rstd = sst[1];
  float sc = g2w[c] * rstd * 0.1f;
  float sb = (g2b[c] - mean * rstd * g2w[c]) * 0.1f;
  u16x8 wv = *(const u16x8*)(wy_b + i);
  u16x8 xv = *(const u16x8*)(xs_b + i);
  float4 o0, o1;
  o0.x = bf2f(wv[0]) * sc + sb + bf2f(xv[0]);
  o0.y = bf2f(wv[1]) * sc + sb + bf2f(xv[1]);
  o0.z = bf2f(wv[2]) * sc + sb + bf2f(xv[2]);
  o0.w = bf2f(wv[3]) * sc + sb + bf2f(xv[3]);
  o1.x = bf2f(wv[4]) * sc + sb + bf2f(xv[4]);
  o1.y = bf2f(wv[5]) * sc + sb + bf2f(xv[5]);
  o1.z = bf2f(wv[6]) * sc + sb + bf2f(xv[6]);
  o1.w = bf2f(wv[7]) * sc + sb + bf2f(xv[7]);
  *(float4*)(out + i) = o0;
  *(float4*)(out + i + 4) = o1;
}

extern "C" void kernel_launch(void* const* d_in, const int* in_sizes, int n_in,
                              void* d_out, int out_size, void* d_ws, size_t ws_size,
                              hipStream_t stream) {
  (void)in_sizes; (void)n_in; (void)out_size; (void)ws_size;
  const float* x   = (const float*)d_in[0];
  const float* sw  = (const float*)d_in[1];
  const float* sb  = (const float*)d_in[2];
  const float* g1w = (const float*)d_in[3];
  const float* g1b = (const float*)d_in[4];
  const float* gw  = (const float*)d_in[5];
  const float* gb  = (const float*)d_in[6];
  const float* thw = (const float*)d_in[7];
  const float* thb = (const float*)d_in[8];
  const float* phw = (const float*)d_in[9];
  const float* phb = (const float*)d_in[10];
  const float* ww  = (const float*)d_in[11];
  const float* wb  = (const float*)d_in[12];
  const float* g2w = (const float*)d_in[13];
  const float* g2b = (const float*)d_in[14];
  float* out = (float*)d_out;
  float* ws = (float*)d_ws;

  // layout (float offsets). R1 proved ws >= 16,778,368 f; high-water = 16,225,408 f.
  ushort_t* xr_b    = (ushort_t*)ws;                   // [B][C][N] u16
  ushort_t* ypart   = (ushort_t*)ws;                   // [B*4][N][Ci] u16 (xr_b dead by attn)
  ushort_t* xs_b    = (ushort_t*)(ws + 4194304);       // [B][C][N] u16
  ushort_t* xbT     = (ushort_t*)(ws + 6291456);       // [B][HW][C] u16 (dead after conv)
  ushort_t* theta_b = (ushort_t*)(ws + 10486912);      // dead after attn
  ushort_t* phi_b   = (ushort_t*)(ws + 11535488);
  ushort_t* g_b     = (ushort_t*)(ws + 12584064);
  ushort_t* xsT     = (ushort_t*)(ws + 13632640);      // dead after proj
  ushort_t* w9      = (ushort_t*)(ws + 15729792);
  ushort_t* wp9     = (ushort_t*)(ws + 16024704);
  ushort_t* wwb     = (ushort_t*)(ws + 16073856);      // ends 16090240 f
  ushort_t* wy_b    = (ushort_t*)(ws + 10486912);      // overlays dead theta+phi
  float*    mpart   = ws + 16090240;                   // 65536 f
  float*    lpart   = ws + 16155776;                   // 65536 f
  float*    part    = ws + 16221312;                   // 4096 f  [32][64][2]

  k_prepack<<<2816, 256, 0, stream>>>(sw, thw, phw, gw, ww, w9, wp9, wwb);
  k_xT<<<dim3(64, 8, 4), 256, 0, stream>>>(x, xbT);
  k_conv_mfma<<<dim3(Hn, Bn), 512, 0, stream>>>(xbT, w9, sb, xr_b, part);
  k_gn1_apply_t<<<dim3(64, 8, 4), 256, 0, stream>>>(xr_b, part, g1w, g1b, xs_b, xsT);
  k_proj_mfma<<<dim3(64, 3, 4), 256, 0, stream>>>(xsT, wp9, thb, phb, gb,
                                                  theta_b, phi_b, g_b);
  k_attn_split<<<1024, 256, 0, stream>>>(theta_b, phi_b, g_b, ypart, mpart, lpart);
  k_wconv_mfma<<<dim3(64, 4), 512, 0, stream>>>(ypart, mpart, lpart, wwb, wb, wy_b, part);
  k_final<<<2048, 256, 0, stream>>>(wy_b, part, g2w, g2b, xs_b, out);
}